// Round 29
// baseline (31.485 us; speedup 1.0000x reference)
//
#include <hip/hip_runtime.h>

// ConvTranspose4d via bf16 MFMA (R29 = R28 + f-PAIR blocks: 6 blocks/CU).
// Gather: out[co,f,od,oh,ow] = sum_{ci,i,kd,kh,kw} x[ci,f+i,id,ih,iw]*W[ci,co,i,kd,kh,kw]
// Stack: R16 E/O fold; R17 LDS staging; R19 od-pair; R22 transposed [n][row];
//   R27 dl-outer; R28 256-thr fine blocks (30.3us best).
// R29: f-triple -> f-PAIR (f0=2fp, 4 staged frames, dl in {0,1}): rows 160->128,
//   LDS 31.1->24.96KB -> 6 blocks/CU (24 waves, was 20): +20% resident phases.
//   Trades R24's +1.5% staging amortization for the overlap axis that gave +4%/step
//   (R27/R28). NRSTR=130 (==2 mod 32 -> 16 even banks, same property as 162).
//   NBLK = 3 x 24 x 48 = 3456 (%8==0). Per-output K-order/bits unchanged ->
//   absmax must stay EXACTLY 0.0078125 (gate).

typedef float  f32x4  __attribute__((ext_vector_type(4)));
typedef float  f4a    __attribute__((ext_vector_type(4)));
typedef short  bf16x8 __attribute__((ext_vector_type(8)));
typedef unsigned int u32;
typedef u32    u32x2  __attribute__((ext_vector_type(2)));
typedef u32    u32x4  __attribute__((ext_vector_type(4)));

namespace {
constexpr int T_ = 8, D_ = 24, H_ = 48, W_ = 48;
constexpr int TO = 6, DO_ = 47, HO = 95, WO = 95;
constexpr int XCS = T_ * D_ * H_ * W_;
constexpr int XFS = D_ * H_ * W_;
constexpr int XDS = H_ * W_;
constexpr long OCS = (long)TO * DO_ * HO * WO;
constexpr int OFS = DO_ * HO * WO;
constexpr int ODS = HO * WO;

constexpr int AG[4] = {24, 12, 12, 8};
constexpr int AOFF[4] = {0, 3072, 4608, 6144};         // shorts; total 7168 = 14 KB
constexpr int NRSTR = 130;                             // per-column row stride (u32)

__global__ __launch_bounds__(256) void pack_kernel(const float* __restrict__ w,
                                                   unsigned short* __restrict__ A) {
  const int tid = blockIdx.x * 256 + threadIdx.x;
  const int nthr = gridDim.x * 256;
  const int KR[4] = {192, 96, 96, 48};
  for (int c = 0; c < 4; ++c) {
    const int cnt = AG[c] * 128;                       // [g][r(16)][j(8)] shorts
    for (int e = tid; e < cnt; e += nthr) {
      const int j = e & 7, r = (e >> 3) & 15, g = e >> 7;
      const int k = g * 8 + j;
      float v = 0.f;
      if (k < KR[c]) {
        int gg = -1, kd = 1, kh = 1;
        const int cc = j & 1;
        if (c == 0)      { gg = g;               kd = ((j >> 1) & 1) ? 2 : 0; kh = ((j >> 2) & 1) ? 0 : 2; }
        else if (c == 1) { gg = 2 * g + (j >> 2); kd = ((j >> 1) & 1) ? 2 : 0; kh = 1; }
        else if (c == 2) { gg = 2 * g + (j >> 2); kd = 1; kh = ((j >> 1) & 1) ? 0 : 2; }
        else             { gg = 4 * g + (j >> 1); kd = 1; kh = 1; }
        if (gg >= 0 && gg < 24) {
          const int ci = gg / 3, i = gg - 3 * (gg / 3);
          const int co = r & 7;
          int kw = (r < 8) ? (cc == 0 ? 1 : -1) : (cc == 0 ? 2 : 0);
          if (kw >= 0) v = w[ci * 648 + co * 81 + i * 27 + kd * 9 + kh * 3 + kw];
        }
      }
      u32 u = __float_as_uint(v);
      u += 0x7FFFu + ((u >> 16) & 1u);                 // RNE to bf16
      A[AOFF[c] + e] = (unsigned short)(u >> 16);
    }
  }
}

// row group base (gg = ci*3+i, dl = f-offset 0..1): gg' = ci*4 + i + dl; 4 rows/gg'
__device__ __forceinline__ int rowb(int gg, int dl) {
  const int ci = gg / 3;
  return (ci * 4 + (gg - 3 * ci) + dl) * 4;
}

template<int PD, int PH>
__device__ __forceinline__ void wave_body(
    const u32* __restrict__ lds, const unsigned short* __restrict__ A,
    float* __restrict__ out, int f0, int od, int oh, int lane)
{
  constexpr int CLS = (PD && PH) ? 0 : PD ? 1 : PH ? 2 : 3;
  constexpr int NSTEP = (CLS == 0) ? 6 : (CLS == 3) ? 2 : 3;
  constexpr int TH = PH;                               // compile-time top h-row
  const int c15 = lane & 15, q = lane >> 4;

  bf16x8 af[NSTEP];
  {
    const unsigned short* Ap = A + AOFF[CLS] + c15 * 8;
    #pragma unroll
    for (int s = 0; s < NSTEP; ++s)
      af[s] = *reinterpret_cast<const bf16x8*>(Ap + (s * 4 + q) * 128);
  }

  const int isO = (q >= 2);
  const int co0 = (q & 1) * 4;

  #pragma unroll
  for (int dl = 0; dl < 2; ++dl) {                     // dl OUTER (R27)
    f32x4 acc[3];
    #pragma unroll
    for (int b = 0; b < 3; ++b) acc[b] = {0, 0, 0, 0};

    #pragma unroll
    for (int blk = 0; blk < 3; ++blk) {
      const int n = blk * 16 + c15;
      const u32* col = lds + n * NRSTR;
      #pragma unroll
      for (int s = 0; s < NSTEP; ++s) {
        const int G = s * 4 + q;
        u32x4 ue;
        if constexpr (CLS == 0) {                      // rows rowb + {0,1,2,3} (TH=1)
          const u32* b = col + rowb(G, dl) + 2 * TH - 2;
          const u32x2 lo = *reinterpret_cast<const u32x2*>(b);
          const u32x2 hi = *reinterpret_cast<const u32x2*>(b + 2);
          ue = u32x4{lo.x, lo.y, hi.x, hi.y};
        } else if constexpr (CLS == 1) {               // (g0,e0),(g0,e1),(g1,e0),(g1,e1)
          const u32* b0 = col + rowb(2 * G, dl) + 2 * TH;
          const u32* b1 = col + rowb(2 * G + 1, dl) + 2 * TH;
          const u32x2 lo = *reinterpret_cast<const u32x2*>(b0);
          const u32x2 hi = *reinterpret_cast<const u32x2*>(b1);
          ue = u32x4{lo.x, lo.y, hi.x, hi.y};
        } else if constexpr (CLS == 2) {               // (g,TH-1),(g,TH) e=1 pairs
          const int r0 = rowb(2 * G, dl), r1 = rowb(2 * G + 1, dl);
          ue = u32x4{col[r0 + 2 * TH - 1], col[r0 + 2 * TH + 1],
                     col[r1 + 2 * TH - 1], col[r1 + 2 * TH + 1]};
        } else {                                       // g ascending, e=1, t=TH
          #pragma unroll
          for (int d = 0; d < 4; ++d) {
            int gg = 4 * G + d; gg = (gg > 23) ? 23 : gg;  // k>=48 -> A==0, row dontcare
            ue[d] = col[rowb(gg, dl) + 2 * TH + 1];
          }
        }
        acc[blk] = __builtin_amdgcn_mfma_f32_16x16x32_bf16(af[s], __builtin_bit_cast(bf16x8, ue), acc[blk], 0, 0, 0);
      }
    }

    // store frame f0+dl: D rows 0-7 = co (even ow), 8-15 = co (odd ow)
    #pragma unroll
    for (int blk = 0; blk < 3; ++blk) {
      const int ow = blk * 32 + 2 * c15 + isO;
      if (ow < 95) {
        const long ob = (long)(f0 + dl) * OFS + (long)od * ODS + (long)oh * HO + ow;
        #pragma unroll
        for (int j = 0; j < 4; ++j)
          out[(long)(co0 + j) * OCS + ob] = acc[blk][j];
      }
    }
  }
}

constexpr int NBLK = 3 * 24 * 48;                      // f-pair x od-pair x og2 = 3456

__global__ __launch_bounds__(256) void convt4d_kernel(
    const float* __restrict__ x, const unsigned short* __restrict__ A,
    float* __restrict__ out)
{
  __shared__ u32 lds[48 * NRSTR];                      // 24960 B -> 6 blocks/CU

  constexpr int qq = NBLK / 8;                         // 432 (NBLK%8==0)
  const int bid = blockIdx.x;
  const int L = (bid & 7) * qq + (bid >> 3);           // bijective XCD swizzle
  const int og2 = L % 48;                              // oh pair {2*og2, 2*og2+1}
  const int rest = L / 48;
  const int odp = rest % 24, fp = rest / 24;           // od pair {2odp,2odp+1}; f-pair
  const int f0 = 2 * fp;                               // f0 in {0,2,4}; frames f0..f0+3

  const int tid = threadIdx.x;
  const int idp = odp + 1;                             // e=0 plane = p+1, e=1 plane = p

  // stage 128-row union PRE-PACKED + TRANSPOSED: lds[n*NRSTR + row] =
  //   bf(x[n]) | bf(x[n+1])<<16 ; row = (ci*4 + fi)*4 + t*2 + e, t in {0,1}, fi 0..3
  for (int row = tid; row < 128; row += 256) {
    const int ggp = row >> 2;
    const int rem = row & 3;
    const int t = rem >> 1, e = rem & 1;
    const int ci = ggp >> 2, fi = ggp & 3;
    int plane = idp - e; if (plane > 23) plane = 23;   // odp=23,e=0: unused, clamp OOB
    int ih = og2 + t; if (ih > 47) ih = 47;            // og2=47,t=1: unused, clamp
    const float* src = x + ci * XCS + (f0 + fi) * XFS + plane * XDS + ih * W_;
    f32x4 v[12];
    #pragma unroll
    for (int ch = 0; ch < 12; ++ch)
      v[ch] = *reinterpret_cast<const f4a*>(src + ch * 4);
    u32* dst = lds + row;
    #pragma unroll
    for (int ch = 0; ch < 12; ++ch) {
      const u32 b0 = __float_as_uint(v[ch].x), b1 = __float_as_uint(v[ch].y);
      const u32 b2 = __float_as_uint(v[ch].z), b3 = __float_as_uint(v[ch].w);
      const u32 b4 = (ch == 11) ? 0u : __float_as_uint(v[ch + 1].x);
      dst[(4 * ch + 0) * NRSTR] = __builtin_amdgcn_perm(b1, b0, 0x07060302u);
      dst[(4 * ch + 1) * NRSTR] = __builtin_amdgcn_perm(b2, b1, 0x07060302u);
      dst[(4 * ch + 2) * NRSTR] = __builtin_amdgcn_perm(b3, b2, 0x07060302u);
      dst[(4 * ch + 3) * NRSTR] = __builtin_amdgcn_perm(b4, b3, 0x07060302u);
    }
  }
  __syncthreads();

  const int w = tid >> 6, lane = tid & 63;
  const int half = w >> 1;                             // 0: od=2p (pd0), 1: od=2p+1 (pd1)
  const int od = 2 * odp + half;
  if (od > 46) return;                                 // odp=23 pd1 half: no od=47
  int oh = og2 * 2 + (w & 1);
  if (oh > 94) oh = 94;                                // og2=47 odd wave: dup of even (benign)
  if (half) {
    if (oh & 1) wave_body<1, 1>(lds, A, out, f0, od, oh, lane);
    else        wave_body<1, 0>(lds, A, out, f0, od, oh, lane);
  } else {
    if (oh & 1) wave_body<0, 1>(lds, A, out, f0, od, oh, lane);
    else        wave_body<0, 0>(lds, A, out, f0, od, oh, lane);
  }
}
}  // namespace

extern "C" void kernel_launch(void* const* d_in, const int* in_sizes, int n_in,
                              void* d_out, int out_size, void* d_ws, size_t ws_size,
                              hipStream_t stream) {
  const float* x = (const float*)d_in[0];
  const float* w = (const float*)d_in[1];
  float* out = (float*)d_out;
  unsigned short* A = (unsigned short*)d_ws;           // 7168 shorts = 14 KB
  hipLaunchKernelGGL(pack_kernel, dim3(8), dim3(256), 0, stream, w, A);
  hipLaunchKernelGGL(convt4d_kernel, dim3(NBLK), dim3(256), 0, stream, x, A, out);
}

// Round 30
// 31.013 us; speedup vs baseline: 1.0152x; 1.0152x over previous
//
#include <hip/hip_runtime.h>

// ConvTranspose4d via bf16 MFMA (R30 = R28 + A-fragment prefetch BEFORE the barrier).
// Gather: out[co,f,od,oh,ow] = sum_{ci,i,kd,kh,kw} x[ci,f+i,id,ih,iw]*W[ci,co,i,kd,kh,kw]
// Stack: R16 E/O fold; R17 LDS staging; R19 od-pair; R22 transposed [n][row];
//   R23/R24 f-triple; R27 dl-outer; R28 256-thr fine blocks (30.3us best).
//   R29 (f-pair, 6 blocks/CU) REVERTED: +20% staging redundancy beat +1 phase (31.5).
// R30: the wave's 16 global b128 A-table loads moved BEFORE __syncthreads -> their
//   ~200-500cy latency overlaps staging writes + barrier wait (compiler cannot hoist
//   globals across a barrier). Fixed af[6] with clamped fragment index (no runtime
//   array indexing -> no scratch; <=4 wasted hot-L1 loads for light classes).
//   Zero math change -> absmax must stay EXACTLY 0.0078125 (gate). VGPR gate <=100.

typedef float  f32x4  __attribute__((ext_vector_type(4)));
typedef float  f4a    __attribute__((ext_vector_type(4)));
typedef short  bf16x8 __attribute__((ext_vector_type(8)));
typedef unsigned int u32;
typedef u32    u32x2  __attribute__((ext_vector_type(2)));
typedef u32    u32x4  __attribute__((ext_vector_type(4)));

namespace {
constexpr int T_ = 8, D_ = 24, H_ = 48, W_ = 48;
constexpr int TO = 6, DO_ = 47, HO = 95, WO = 95;
constexpr int XCS = T_ * D_ * H_ * W_;
constexpr int XFS = D_ * H_ * W_;
constexpr int XDS = H_ * W_;
constexpr long OCS = (long)TO * DO_ * HO * WO;
constexpr int OFS = DO_ * HO * WO;
constexpr int ODS = HO * WO;

constexpr int AG[4] = {24, 12, 12, 8};
constexpr int AOFF[4] = {0, 3072, 4608, 6144};         // shorts; total 7168 = 14 KB
constexpr int NRSTR = 162;                             // per-column row stride (u32)

__global__ __launch_bounds__(256) void pack_kernel(const float* __restrict__ w,
                                                   unsigned short* __restrict__ A) {
  const int tid = blockIdx.x * 256 + threadIdx.x;
  const int nthr = gridDim.x * 256;
  const int KR[4] = {192, 96, 96, 48};
  for (int c = 0; c < 4; ++c) {
    const int cnt = AG[c] * 128;                       // [g][r(16)][j(8)] shorts
    for (int e = tid; e < cnt; e += nthr) {
      const int j = e & 7, r = (e >> 3) & 15, g = e >> 7;
      const int k = g * 8 + j;
      float v = 0.f;
      if (k < KR[c]) {
        int gg = -1, kd = 1, kh = 1;
        const int cc = j & 1;
        if (c == 0)      { gg = g;               kd = ((j >> 1) & 1) ? 2 : 0; kh = ((j >> 2) & 1) ? 0 : 2; }
        else if (c == 1) { gg = 2 * g + (j >> 2); kd = ((j >> 1) & 1) ? 2 : 0; kh = 1; }
        else if (c == 2) { gg = 2 * g + (j >> 2); kd = 1; kh = ((j >> 1) & 1) ? 0 : 2; }
        else             { gg = 4 * g + (j >> 1); kd = 1; kh = 1; }
        if (gg >= 0 && gg < 24) {
          const int ci = gg / 3, i = gg - 3 * (gg / 3);
          const int co = r & 7;
          int kw = (r < 8) ? (cc == 0 ? 1 : -1) : (cc == 0 ? 2 : 0);
          if (kw >= 0) v = w[ci * 648 + co * 81 + i * 27 + kd * 9 + kh * 3 + kw];
        }
      }
      u32 u = __float_as_uint(v);
      u += 0x7FFFu + ((u >> 16) & 1u);                 // RNE to bf16
      A[AOFF[c] + e] = (unsigned short)(u >> 16);
    }
  }
}

// row group base (gg = ci*3+i, dl = f-offset 0..2): gg' = ci*5 + i + dl; 4 rows/gg'
__device__ __forceinline__ int rowb(int gg, int dl) {
  const int ci = gg / 3;
  return (ci * 5 + (gg - 3 * ci) + dl) * 4;
}

template<int PD, int PH>
__device__ __forceinline__ void wave_body(
    const u32* __restrict__ lds, const bf16x8 (&af)[6],
    float* __restrict__ out, int f0, int od, int oh, int lane)
{
  constexpr int CLS = (PD && PH) ? 0 : PD ? 1 : PH ? 2 : 3;
  constexpr int NSTEP = (CLS == 0) ? 6 : (CLS == 3) ? 2 : 3;
  constexpr int TH = PH;                               // compile-time top h-row
  const int c15 = lane & 15, q = lane >> 4;

  const int isO = (q >= 2);
  const int co0 = (q & 1) * 4;

  #pragma unroll
  for (int dl = 0; dl < 3; ++dl) {                     // dl OUTER (R27)
    f32x4 acc[3];
    #pragma unroll
    for (int b = 0; b < 3; ++b) acc[b] = {0, 0, 0, 0};

    #pragma unroll
    for (int blk = 0; blk < 3; ++blk) {
      const int n = blk * 16 + c15;
      const u32* col = lds + n * NRSTR;
      #pragma unroll
      for (int s = 0; s < NSTEP; ++s) {
        const int G = s * 4 + q;
        u32x4 ue;
        if constexpr (CLS == 0) {                      // rows rowb + {0,1,2,3} (TH=1)
          const u32* b = col + rowb(G, dl) + 2 * TH - 2;
          const u32x2 lo = *reinterpret_cast<const u32x2*>(b);
          const u32x2 hi = *reinterpret_cast<const u32x2*>(b + 2);
          ue = u32x4{lo.x, lo.y, hi.x, hi.y};
        } else if constexpr (CLS == 1) {               // (g0,e0),(g0,e1),(g1,e0),(g1,e1)
          const u32* b0 = col + rowb(2 * G, dl) + 2 * TH;
          const u32* b1 = col + rowb(2 * G + 1, dl) + 2 * TH;
          const u32x2 lo = *reinterpret_cast<const u32x2*>(b0);
          const u32x2 hi = *reinterpret_cast<const u32x2*>(b1);
          ue = u32x4{lo.x, lo.y, hi.x, hi.y};
        } else if constexpr (CLS == 2) {               // (g,TH-1),(g,TH) e=1 pairs
          const int r0 = rowb(2 * G, dl), r1 = rowb(2 * G + 1, dl);
          ue = u32x4{col[r0 + 2 * TH - 1], col[r0 + 2 * TH + 1],
                     col[r1 + 2 * TH - 1], col[r1 + 2 * TH + 1]};
        } else {                                       // g ascending, e=1, t=TH
          #pragma unroll
          for (int d = 0; d < 4; ++d) {
            int gg = 4 * G + d; gg = (gg > 23) ? 23 : gg;  // k>=48 -> A==0, row dontcare
            ue[d] = col[rowb(gg, dl) + 2 * TH + 1];
          }
        }
        acc[blk] = __builtin_amdgcn_mfma_f32_16x16x32_bf16(af[s], __builtin_bit_cast(bf16x8, ue), acc[blk], 0, 0, 0);
      }
    }

    // store frame f0+dl: D rows 0-7 = co (even ow), 8-15 = co (odd ow)
    #pragma unroll
    for (int blk = 0; blk < 3; ++blk) {
      const int ow = blk * 32 + 2 * c15 + isO;
      if (ow < 95) {
        const long ob = (long)(f0 + dl) * OFS + (long)od * ODS + (long)oh * HO + ow;
        #pragma unroll
        for (int j = 0; j < 4; ++j)
          out[(long)(co0 + j) * OCS + ob] = acc[blk][j];
      }
    }
  }
}

constexpr int NBLK = 2 * 24 * 48;                      // f-triple x od-pair x og2 = 2304

__global__ __launch_bounds__(256) void convt4d_kernel(
    const float* __restrict__ x, const unsigned short* __restrict__ A,
    float* __restrict__ out)
{
  __shared__ u32 lds[48 * NRSTR];                      // 31104 B -> 5 blocks/CU

  constexpr int qq = NBLK / 8;                         // 288 (NBLK%8==0)
  const int bid = blockIdx.x;
  const int L = (bid & 7) * qq + (bid >> 3);           // bijective XCD swizzle
  const int og2 = L % 48;                              // oh pair {2*og2, 2*og2+1}
  const int rest = L / 48;
  const int odp = rest % 24, fp = rest / 24;           // od pair {2odp,2odp+1}; f-triple
  const int f0 = 3 * fp;                               // f0 in {0,3}; frames f0..f0+4

  const int tid = threadIdx.x;
  const int idp = odp + 1;                             // e=0 plane = p+1, e=1 plane = p

  // stage 160-row union PRE-PACKED + TRANSPOSED: lds[n*NRSTR + row] =
  //   bf(x[n]) | bf(x[n+1])<<16 ; row = (ci*5 + fi)*4 + t*2 + e, t in {0,1}
  for (int row = tid; row < 160; row += 256) {
    const int ggp = row >> 2;
    const int rem = row & 3;
    const int t = rem >> 1, e = rem & 1;
    const int ci = ggp / 5, fi = ggp % 5;
    int plane = idp - e; if (plane > 23) plane = 23;   // odp=23,e=0: unused, clamp OOB
    int ih = og2 + t; if (ih > 47) ih = 47;            // og2=47,t=1: unused, clamp
    const float* src = x + ci * XCS + (f0 + fi) * XFS + plane * XDS + ih * W_;
    f32x4 v[12];
    #pragma unroll
    for (int ch = 0; ch < 12; ++ch)
      v[ch] = *reinterpret_cast<const f4a*>(src + ch * 4);
    u32* dst = lds + row;
    #pragma unroll
    for (int ch = 0; ch < 12; ++ch) {
      const u32 b0 = __float_as_uint(v[ch].x), b1 = __float_as_uint(v[ch].y);
      const u32 b2 = __float_as_uint(v[ch].z), b3 = __float_as_uint(v[ch].w);
      const u32 b4 = (ch == 11) ? 0u : __float_as_uint(v[ch + 1].x);
      dst[(4 * ch + 0) * NRSTR] = __builtin_amdgcn_perm(b1, b0, 0x07060302u);
      dst[(4 * ch + 1) * NRSTR] = __builtin_amdgcn_perm(b2, b1, 0x07060302u);
      dst[(4 * ch + 2) * NRSTR] = __builtin_amdgcn_perm(b3, b2, 0x07060302u);
      dst[(4 * ch + 3) * NRSTR] = __builtin_amdgcn_perm(b4, b3, 0x07060302u);
    }
  }

  // --- R30: wave decode + A-fragment prefetch BEFORE the barrier ---
  const int w = tid >> 6, lane = tid & 63;
  const int half = w >> 1;                             // 0: od=2p (pd0), 1: od=2p+1 (pd1)
  const int od = 2 * odp + half;
  int oh = og2 * 2 + (w & 1);
  if (oh > 94) oh = 94;                                // og2=47 odd wave: dup of even (benign)
  const int ph = oh & 1;
  const int cls = half ? (ph ? 0 : 1) : (ph ? 2 : 3);
  const int nstep = (cls == 0) ? 6 : (cls == 3) ? 2 : 3;
  const int c15 = lane & 15, q = lane >> 4;
  bf16x8 af[6];
  {
    const unsigned short* Ap = A + AOFF[cls] + c15 * 8;
    #pragma unroll
    for (int s = 0; s < 6; ++s) {                      // clamped index: in-bounds per class
      const int ss = (s < nstep) ? s : (nstep - 1);
      af[s] = *reinterpret_cast<const bf16x8*>(Ap + (ss * 4 + q) * 128);
    }
  }
  __syncthreads();

  if (od > 46) return;                                 // odp=23 pd1 half: no od=47
  if (half) {
    if (ph) wave_body<1, 1>(lds, af, out, f0, od, oh, lane);
    else    wave_body<1, 0>(lds, af, out, f0, od, oh, lane);
  } else {
    if (ph) wave_body<0, 1>(lds, af, out, f0, od, oh, lane);
    else    wave_body<0, 0>(lds, af, out, f0, od, oh, lane);
  }
}
}  // namespace

extern "C" void kernel_launch(void* const* d_in, const int* in_sizes, int n_in,
                              void* d_out, int out_size, void* d_ws, size_t ws_size,
                              hipStream_t stream) {
  const float* x = (const float*)d_in[0];
  const float* w = (const float*)d_in[1];
  float* out = (float*)d_out;
  unsigned short* A = (unsigned short*)d_ws;           // 7168 shorts = 14 KB
  hipLaunchKernelGGL(pack_kernel, dim3(8), dim3(256), 0, stream, w, A);
  hipLaunchKernelGGL(convt4d_kernel, dim3(NBLK), dim3(256), 0, stream, x, A, out);
}

// Round 31
// 30.477 us; speedup vs baseline: 1.0331x; 1.0176x over previous
//
#include <hip/hip_runtime.h>

// ConvTranspose4d via bf16 MFMA (R31 = R28 + s_setprio(1) around the compute cluster).
// Gather: out[co,f,od,oh,ow] = sum_{ci,i,kd,kh,kw} x[ci,f+i,id,ih,iw]*W[ci,co,i,kd,kh,kw]
// Stack: R16 E/O fold; R17 LDS staging; R19 od-pair; R22 transposed [n][row];
//   R23/R24 f-triple; R27 dl-outer; R28 256-thr fine blocks (30.3us best).
//   R29 (6 blocks/CU) and R30 (A-prefetch) both REVERTED (31.5 / 31.0).
// R31: T5 setprio. Mechanism requires wave ROLE DIVERSITY on the CU: 5 co-resident
//   blocks sit at different phases (some staging = VMEM/ds_write, some computing =
//   MFMA/ds_read). Boost only the compute cluster -> compute waves win issue
//   arbitration; staging waves' memory ops proceed in background. This is the attn-win
//   regime (+4-7%), not the lockstep-GEMM null. Zero math change -> absmax EXACTLY
//   0.0078125 (gate). A/B vs 30.3: >=30.5 -> T5 null, R28 final.

typedef float  f32x4  __attribute__((ext_vector_type(4)));
typedef float  f4a    __attribute__((ext_vector_type(4)));
typedef short  bf16x8 __attribute__((ext_vector_type(8)));
typedef unsigned int u32;
typedef u32    u32x2  __attribute__((ext_vector_type(2)));
typedef u32    u32x4  __attribute__((ext_vector_type(4)));

namespace {
constexpr int T_ = 8, D_ = 24, H_ = 48, W_ = 48;
constexpr int TO = 6, DO_ = 47, HO = 95, WO = 95;
constexpr int XCS = T_ * D_ * H_ * W_;
constexpr int XFS = D_ * H_ * W_;
constexpr int XDS = H_ * W_;
constexpr long OCS = (long)TO * DO_ * HO * WO;
constexpr int OFS = DO_ * HO * WO;
constexpr int ODS = HO * WO;

constexpr int AG[4] = {24, 12, 12, 8};
constexpr int AOFF[4] = {0, 3072, 4608, 6144};         // shorts; total 7168 = 14 KB
constexpr int NRSTR = 162;                             // per-column row stride (u32)

__global__ __launch_bounds__(256) void pack_kernel(const float* __restrict__ w,
                                                   unsigned short* __restrict__ A) {
  const int tid = blockIdx.x * 256 + threadIdx.x;
  const int nthr = gridDim.x * 256;
  const int KR[4] = {192, 96, 96, 48};
  for (int c = 0; c < 4; ++c) {
    const int cnt = AG[c] * 128;                       // [g][r(16)][j(8)] shorts
    for (int e = tid; e < cnt; e += nthr) {
      const int j = e & 7, r = (e >> 3) & 15, g = e >> 7;
      const int k = g * 8 + j;
      float v = 0.f;
      if (k < KR[c]) {
        int gg = -1, kd = 1, kh = 1;
        const int cc = j & 1;
        if (c == 0)      { gg = g;               kd = ((j >> 1) & 1) ? 2 : 0; kh = ((j >> 2) & 1) ? 0 : 2; }
        else if (c == 1) { gg = 2 * g + (j >> 2); kd = ((j >> 1) & 1) ? 2 : 0; kh = 1; }
        else if (c == 2) { gg = 2 * g + (j >> 2); kd = 1; kh = ((j >> 1) & 1) ? 0 : 2; }
        else             { gg = 4 * g + (j >> 1); kd = 1; kh = 1; }
        if (gg >= 0 && gg < 24) {
          const int ci = gg / 3, i = gg - 3 * (gg / 3);
          const int co = r & 7;
          int kw = (r < 8) ? (cc == 0 ? 1 : -1) : (cc == 0 ? 2 : 0);
          if (kw >= 0) v = w[ci * 648 + co * 81 + i * 27 + kd * 9 + kh * 3 + kw];
        }
      }
      u32 u = __float_as_uint(v);
      u += 0x7FFFu + ((u >> 16) & 1u);                 // RNE to bf16
      A[AOFF[c] + e] = (unsigned short)(u >> 16);
    }
  }
}

// row group base (gg = ci*3+i, dl = f-offset 0..2): gg' = ci*5 + i + dl; 4 rows/gg'
__device__ __forceinline__ int rowb(int gg, int dl) {
  const int ci = gg / 3;
  return (ci * 5 + (gg - 3 * ci) + dl) * 4;
}

template<int PD, int PH>
__device__ __forceinline__ void wave_body(
    const u32* __restrict__ lds, const unsigned short* __restrict__ A,
    float* __restrict__ out, int f0, int od, int oh, int lane)
{
  constexpr int CLS = (PD && PH) ? 0 : PD ? 1 : PH ? 2 : 3;
  constexpr int NSTEP = (CLS == 0) ? 6 : (CLS == 3) ? 2 : 3;
  constexpr int TH = PH;                               // compile-time top h-row
  const int c15 = lane & 15, q = lane >> 4;

  bf16x8 af[NSTEP];
  {
    const unsigned short* Ap = A + AOFF[CLS] + c15 * 8;
    #pragma unroll
    for (int s = 0; s < NSTEP; ++s)
      af[s] = *reinterpret_cast<const bf16x8*>(Ap + (s * 4 + q) * 128);
  }

  const int isO = (q >= 2);
  const int co0 = (q & 1) * 4;

  #pragma unroll
  for (int dl = 0; dl < 3; ++dl) {                     // dl OUTER (R27)
    f32x4 acc[3];
    #pragma unroll
    for (int b = 0; b < 3; ++b) acc[b] = {0, 0, 0, 0};

    __builtin_amdgcn_s_setprio(1);                     // R31: boost compute cluster
    #pragma unroll
    for (int blk = 0; blk < 3; ++blk) {
      const int n = blk * 16 + c15;
      const u32* col = lds + n * NRSTR;
      #pragma unroll
      for (int s = 0; s < NSTEP; ++s) {
        const int G = s * 4 + q;
        u32x4 ue;
        if constexpr (CLS == 0) {                      // rows rowb + {0,1,2,3} (TH=1)
          const u32* b = col + rowb(G, dl) + 2 * TH - 2;
          const u32x2 lo = *reinterpret_cast<const u32x2*>(b);
          const u32x2 hi = *reinterpret_cast<const u32x2*>(b + 2);
          ue = u32x4{lo.x, lo.y, hi.x, hi.y};
        } else if constexpr (CLS == 1) {               // (g0,e0),(g0,e1),(g1,e0),(g1,e1)
          const u32* b0 = col + rowb(2 * G, dl) + 2 * TH;
          const u32* b1 = col + rowb(2 * G + 1, dl) + 2 * TH;
          const u32x2 lo = *reinterpret_cast<const u32x2*>(b0);
          const u32x2 hi = *reinterpret_cast<const u32x2*>(b1);
          ue = u32x4{lo.x, lo.y, hi.x, hi.y};
        } else if constexpr (CLS == 2) {               // (g,TH-1),(g,TH) e=1 pairs
          const int r0 = rowb(2 * G, dl), r1 = rowb(2 * G + 1, dl);
          ue = u32x4{col[r0 + 2 * TH - 1], col[r0 + 2 * TH + 1],
                     col[r1 + 2 * TH - 1], col[r1 + 2 * TH + 1]};
        } else {                                       // g ascending, e=1, t=TH
          #pragma unroll
          for (int d = 0; d < 4; ++d) {
            int gg = 4 * G + d; gg = (gg > 23) ? 23 : gg;  // k>=48 -> A==0, row dontcare
            ue[d] = col[rowb(gg, dl) + 2 * TH + 1];
          }
        }
        acc[blk] = __builtin_amdgcn_mfma_f32_16x16x32_bf16(af[s], __builtin_bit_cast(bf16x8, ue), acc[blk], 0, 0, 0);
      }
    }
    __builtin_amdgcn_s_setprio(0);                     // stores at normal priority

    // store frame f0+dl: D rows 0-7 = co (even ow), 8-15 = co (odd ow)
    #pragma unroll
    for (int blk = 0; blk < 3; ++blk) {
      const int ow = blk * 32 + 2 * c15 + isO;
      if (ow < 95) {
        const long ob = (long)(f0 + dl) * OFS + (long)od * ODS + (long)oh * HO + ow;
        #pragma unroll
        for (int j = 0; j < 4; ++j)
          out[(long)(co0 + j) * OCS + ob] = acc[blk][j];
      }
    }
  }
}

constexpr int NBLK = 2 * 24 * 48;                      // f-triple x od-pair x og2 = 2304

__global__ __launch_bounds__(256) void convt4d_kernel(
    const float* __restrict__ x, const unsigned short* __restrict__ A,
    float* __restrict__ out)
{
  __shared__ u32 lds[48 * NRSTR];                      // 31104 B -> 5 blocks/CU

  constexpr int qq = NBLK / 8;                         // 288 (NBLK%8==0)
  const int bid = blockIdx.x;
  const int L = (bid & 7) * qq + (bid >> 3);           // bijective XCD swizzle
  const int og2 = L % 48;                              // oh pair {2*og2, 2*og2+1}
  const int rest = L / 48;
  const int odp = rest % 24, fp = rest / 24;           // od pair {2odp,2odp+1}; f-triple
  const int f0 = 3 * fp;                               // f0 in {0,3}; frames f0..f0+4

  const int tid = threadIdx.x;
  const int idp = odp + 1;                             // e=0 plane = p+1, e=1 plane = p

  // stage 160-row union PRE-PACKED + TRANSPOSED: lds[n*NRSTR + row] =
  //   bf(x[n]) | bf(x[n+1])<<16 ; row = (ci*5 + fi)*4 + t*2 + e, t in {0,1}
  for (int row = tid; row < 160; row += 256) {
    const int ggp = row >> 2;
    const int rem = row & 3;
    const int t = rem >> 1, e = rem & 1;
    const int ci = ggp / 5, fi = ggp % 5;
    int plane = idp - e; if (plane > 23) plane = 23;   // odp=23,e=0: unused, clamp OOB
    int ih = og2 + t; if (ih > 47) ih = 47;            // og2=47,t=1: unused, clamp
    const float* src = x + ci * XCS + (f0 + fi) * XFS + plane * XDS + ih * W_;
    f32x4 v[12];
    #pragma unroll
    for (int ch = 0; ch < 12; ++ch)
      v[ch] = *reinterpret_cast<const f4a*>(src + ch * 4);
    u32* dst = lds + row;
    #pragma unroll
    for (int ch = 0; ch < 12; ++ch) {
      const u32 b0 = __float_as_uint(v[ch].x), b1 = __float_as_uint(v[ch].y);
      const u32 b2 = __float_as_uint(v[ch].z), b3 = __float_as_uint(v[ch].w);
      const u32 b4 = (ch == 11) ? 0u : __float_as_uint(v[ch + 1].x);
      dst[(4 * ch + 0) * NRSTR] = __builtin_amdgcn_perm(b1, b0, 0x07060302u);
      dst[(4 * ch + 1) * NRSTR] = __builtin_amdgcn_perm(b2, b1, 0x07060302u);
      dst[(4 * ch + 2) * NRSTR] = __builtin_amdgcn_perm(b3, b2, 0x07060302u);
      dst[(4 * ch + 3) * NRSTR] = __builtin_amdgcn_perm(b4, b3, 0x07060302u);
    }
  }
  __syncthreads();

  const int w = tid >> 6, lane = tid & 63;
  const int half = w >> 1;                             // 0: od=2p (pd0), 1: od=2p+1 (pd1)
  const int od = 2 * odp + half;
  if (od > 46) return;                                 // odp=23 pd1 half: no od=47
  int oh = og2 * 2 + (w & 1);
  if (oh > 94) oh = 94;                                // og2=47 odd wave: dup of even (benign)
  if (half) {
    if (oh & 1) wave_body<1, 1>(lds, A, out, f0, od, oh, lane);
    else        wave_body<1, 0>(lds, A, out, f0, od, oh, lane);
  } else {
    if (oh & 1) wave_body<0, 1>(lds, A, out, f0, od, oh, lane);
    else        wave_body<0, 0>(lds, A, out, f0, od, oh, lane);
  }
}
}  // namespace

extern "C" void kernel_launch(void* const* d_in, const int* in_sizes, int n_in,
                              void* d_out, int out_size, void* d_ws, size_t ws_size,
                              hipStream_t stream) {
  const float* x = (const float*)d_in[0];
  const float* w = (const float*)d_in[1];
  float* out = (float*)d_out;
  unsigned short* A = (unsigned short*)d_ws;           // 7168 shorts = 14 KB
  hipLaunchKernelGGL(pack_kernel, dim3(8), dim3(256), 0, stream, w, A);
  hipLaunchKernelGGL(convt4d_kernel, dim3(NBLK), dim3(256), 0, stream, x, A, out);
}